// Round 3
// baseline (308.512 us; speedup 1.0000x reference)
//
#include <hip/hip_runtime.h>
#include <hip/hip_bf16.h>

// NT-Xent with more negatives: N=2048, D=128, k=4 augs.
// sim = norm(z[4096,128]) @ norm(z_all[8192,128])^T * 2   (T=0.5)
// loss = mean_rows( logsumexp(masked sim) - pos )
// Strategy: bf16 MFMA GEMM, UNMASKED sum of exp(sim-2) (fixed max M=2),
// masked diagonal terms subtracted analytically in a last-block finisher.

#define NN      2048
#define DD      128
#define TWO_N   4096
#define FOUR_N  8192
#define BM      128
#define BN      128
#define CT      64     // 8192 / BN column tiles

using frag_ab = __attribute__((ext_vector_type(8))) short;  // 8 bf16 = 16 B
using f32x4   = __attribute__((ext_vector_type(4))) float;

__device__ inline void gl_lds16(const short* g, short* l) {
  __builtin_amdgcn_global_load_lds(
      (const __attribute__((address_space(1))) void*)g,
      (__attribute__((address_space(3))) void*)l, 16, 0, 0);
}

// XOR swizzle: LDS chunk (row,pos) holds global chunk (row, pos^(row&15)).
// 16B chunks, 16 per 256B row. Kills the 16-way ds_read_b128 bank conflict.
__device__ inline int swz(int chunk) {
  return (chunk & ~15) | ((chunk & 15) ^ ((chunk >> 4) & 15));
}

// ---------------- Kernel 1: L2-normalize rows -> bf16; init out/counters ----
__global__ __launch_bounds__(256) void knorm(const float* __restrict__ p0,
                                             const float* __restrict__ p1,
                                             const float* __restrict__ p2,
                                             const float* __restrict__ p3,
                                             short* __restrict__ Bn,
                                             int* __restrict__ cnt,
                                             float* __restrict__ out) {
  if (blockIdx.x == 0) {
    if (threadIdx.x < 32) cnt[threadIdx.x] = 0;
    if (threadIdx.x == 32) out[0] = 0.0f;
  }
  int wave = threadIdx.x >> 6, lane = threadIdx.x & 63;
  int row = blockIdx.x * 4 + wave;                 // 0..8191
  int q = row >> 11, idx = row & (NN - 1);
  const float* src = (q == 0) ? p0 : (q == 1) ? p1 : (q == 2) ? p2 : p3;
  const float2* s2 = (const float2*)(src + (size_t)idx * DD);
  float2 v = s2[lane];
  float ss = v.x * v.x + v.y * v.y;
  #pragma unroll
  for (int sh = 1; sh < 64; sh <<= 1) ss += __shfl_xor(ss, sh, 64);
  float inv = 1.0f / fmaxf(sqrtf(ss), 1e-8f);
  __hip_bfloat162 o;
  o.x = __float2bfloat16(v.x * inv);
  o.y = __float2bfloat16(v.y * inv);
  ((__hip_bfloat162*)(Bn + (size_t)row * DD))[lane] = o;
}

// ---------------- Kernel 2: GEMM + unmasked partial sumexp + finisher -------
// Grid (32 row tiles, 64 col tiles). 128x128 tile, 4 waves x 64x64 quadrant.
// pS[row][tile] = sum_cols_in_tile exp(2*sim - 2). Last block per row-group
// merges, corrects masked diagonals, computes pos, atomicAdds loss.
__global__ __launch_bounds__(256) void kgemm(const short* __restrict__ Bn,
                                             float* __restrict__ pS,
                                             int* __restrict__ cnt,
                                             float* __restrict__ out) {
  __shared__ short sA[BM * DD];   // 32 KB (swizzled)
  __shared__ short sB[BN * DD];   // 32 KB (swizzled)
  __shared__ float sS[BM][2];
  __shared__ float sRed[4];
  __shared__ int   isLast;

  int t = threadIdx.x, wave = t >> 6, lane = t & 63;
  int quad = lane >> 4, l16 = lane & 15;

  const short* gA = Bn + (size_t)blockIdx.x * BM * DD;
  const short* gB = Bn + (size_t)blockIdx.y * BN * DD;
  #pragma unroll
  for (int i = 0; i < 8; ++i) {
    int c0 = i * 256 + wave * 64;                  // lane-0 LDS chunk index
    gl_lds16(gA + (size_t)swz(c0 + lane) * 8, sA + (size_t)c0 * 8);
    gl_lds16(gB + (size_t)swz(c0 + lane) * 8, sB + (size_t)c0 * 8);
  }
  __syncthreads();

  int rowHalf = wave >> 1, colHalf = wave & 1;
  f32x4 acc[4][4];
  #pragma unroll
  for (int rf = 0; rf < 4; ++rf)
    #pragma unroll
    for (int cf = 0; cf < 4; ++cf) acc[rf][cf] = (f32x4){0.f, 0.f, 0.f, 0.f};

  #pragma unroll
  for (int k = 0; k < 4; ++k) {
    frag_ab a[4], b[4];
    #pragma unroll
    for (int rf = 0; rf < 4; ++rf) {
      int r_ = rowHalf * 64 + rf * 16 + l16;       // r_ & 15 == l16
      a[rf] = *(const frag_ab*)&sA[(size_t)((r_ << 4) | ((k * 4 + quad) ^ l16)) * 8];
    }
    #pragma unroll
    for (int cf = 0; cf < 4; ++cf) {
      int r_ = colHalf * 64 + cf * 16 + l16;
      b[cf] = *(const frag_ab*)&sB[(size_t)((r_ << 4) | ((k * 4 + quad) ^ l16)) * 8];
    }
    #pragma unroll
    for (int rf = 0; rf < 4; ++rf)
      #pragma unroll
      for (int cf = 0; cf < 4; ++cf)
        acc[rf][cf] = __builtin_amdgcn_mfma_f32_16x16x32_bf16(a[rf], b[cf], acc[rf][cf], 0, 0, 0);
  }

  // Epilogue: S_partial = sum exp(2*sim - 2) over this wave's 64 cols, no mask.
  int grBase = blockIdx.x * BM;
  #pragma unroll
  for (int rf = 0; rf < 4; ++rf) {
    #pragma unroll
    for (int r = 0; r < 4; ++r) {
      int rowLocal = rowHalf * 64 + rf * 16 + quad * 4 + r;
      float s = 0.f;
      #pragma unroll
      for (int cf = 0; cf < 4; ++cf)
        s += __expf(fmaf(acc[rf][cf][r], 2.0f, -2.0f));
      #pragma unroll
      for (int sh = 1; sh < 16; sh <<= 1) s += __shfl_xor(s, sh, 64);
      if (l16 == 0) sS[rowLocal][colHalf] = s;
    }
  }
  __syncthreads();
  if (t < BM)
    pS[(size_t)(grBase + t) * CT + blockIdx.y] = sS[t][0] + sS[t][1];

  // ---- last-block-per-row-group finisher ----
  __threadfence();                                  // release pS stores
  if (t == 0) {
    int old = atomicAdd(&cnt[blockIdx.x], 1);
    isLast = (old == (int)gridDim.y - 1);
  }
  __syncthreads();
  if (!isLast) return;
  __threadfence();                                  // acquire others' pS stores

  float wloss = 0.f;                                // valid on lane 0
  for (int rr = wave; rr < BM; rr += 4) {           // 32 rows per wave
    int gr = grBase + rr;
    int idx = gr & (NN - 1), half = gr >> 11;
    float S = pS[(size_t)gr * CT + lane];           // coalesced: 64 tiles
    #pragma unroll
    for (int sh = 1; sh < 64; sh <<= 1) S += __shfl_xor(S, sh, 64);
    // dots vs: self (gr), pos ((1-half)*NN+idx), aug3 (4096+idx), aug4 (6144+idx)
    unsigned int ua = ((const unsigned int*)(Bn + (size_t)gr * DD))[lane];
    unsigned int ub = ((const unsigned int*)(Bn + (size_t)((1 - half) * NN + idx) * DD))[lane];
    unsigned int uc = ((const unsigned int*)(Bn + (size_t)(2 * NN + idx) * DD))[lane];
    unsigned int ud = ((const unsigned int*)(Bn + (size_t)(3 * NN + idx) * DD))[lane];
    float a0 = __uint_as_float((ua & 0xffffu) << 16), a1 = __uint_as_float(ua & 0xffff0000u);
    float b0 = __uint_as_float((ub & 0xffffu) << 16), b1 = __uint_as_float(ub & 0xffff0000u);
    float c0 = __uint_as_float((uc & 0xffffu) << 16), c1 = __uint_as_float(uc & 0xffff0000u);
    float d0 = __uint_as_float((ud & 0xffffu) << 16), d1 = __uint_as_float(ud & 0xffff0000u);
    float daa = a0 * a0 + a1 * a1;
    float dab = a0 * b0 + a1 * b1;
    float dac = a0 * c0 + a1 * c1;
    float dad = a0 * d0 + a1 * d1;
    #pragma unroll
    for (int sh = 1; sh < 64; sh <<= 1) {
      daa += __shfl_xor(daa, sh, 64);
      dab += __shfl_xor(dab, sh, 64);
      dac += __shfl_xor(dac, sh, 64);
      dad += __shfl_xor(dad, sh, 64);
    }
    // subtract masked diagonals: self + aug3 + aug4 (pos block stays)
    float Sc = S - __expf(fmaf(daa, 2.0f, -2.0f))
                 - __expf(fmaf(dac, 2.0f, -2.0f))
                 - __expf(fmaf(dad, 2.0f, -2.0f));
    float loss = (2.0f + __logf(Sc)) - 2.0f * dab;
    if (lane == 0) wloss += loss;
  }
  if (lane == 0) sRed[wave] = wloss;
  __syncthreads();
  if (t == 0)
    atomicAdd(out, (sRed[0] + sRed[1] + sRed[2] + sRed[3]) * (1.0f / (float)TWO_N));
}

extern "C" void kernel_launch(void* const* d_in, const int* in_sizes, int n_in,
                              void* d_out, int out_size, void* d_ws, size_t ws_size,
                              hipStream_t stream) {
  (void)in_sizes; (void)n_in; (void)out_size; (void)ws_size;
  const float* p0 = (const float*)d_in[0];
  const float* p1 = (const float*)d_in[1];
  const float* p2 = (const float*)d_in[2];
  const float* p3 = (const float*)d_in[3];

  // ws layout: Bn bf16 [8192][128] (2 MB) | pS f32 [4096][64] (1 MB) | cnt[32]
  short* Bn = (short*)d_ws;
  float* pS = (float*)((char*)d_ws + (size_t)FOUR_N * DD * sizeof(short));
  int* cnt = (int*)(pS + (size_t)TWO_N * CT);
  float* out = (float*)d_out;

  knorm<<<FOUR_N / 4, 256, 0, stream>>>(p0, p1, p2, p3, Bn, cnt, out);
  kgemm<<<dim3(TWO_N / BM, FOUR_N / BN), 256, 0, stream>>>(Bn, pS, cnt, out);
}

// Round 4
// 110.385 us; speedup vs baseline: 2.7949x; 2.7949x over previous
//
#include <hip/hip_runtime.h>
#include <hip/hip_bf16.h>

// NT-Xent with more negatives: N=2048, D=128, k=4 augs.
// sim = norm(z[4096,128]) @ norm(z_all[8192,128])^T * 2   (T=0.5)
// loss = mean_rows( logsumexp(masked sim) - pos )
// Strategy: bf16 MFMA GEMM, UNMASKED sum of exp(2*sim-2) (fixed max M=2),
// masked diagonal terms subtracted analytically in a separate finisher
// kernel (kernel boundary = the sync; NO device-scope fences — R3 showed
// per-block __threadfence() costs ~200us via L2 writeback storms).

#define NN      2048
#define DD      128
#define TWO_N   4096
#define FOUR_N  8192
#define BM      128
#define BN      128
#define CT      64     // 8192 / BN column tiles

using frag_ab = __attribute__((ext_vector_type(8))) short;  // 8 bf16 = 16 B
using f32x4   = __attribute__((ext_vector_type(4))) float;

__device__ inline void gl_lds16(const short* g, short* l) {
  __builtin_amdgcn_global_load_lds(
      (const __attribute__((address_space(1))) void*)g,
      (__attribute__((address_space(3))) void*)l, 16, 0, 0);
}

// XOR swizzle: LDS chunk (row,pos) holds global chunk (row, pos^(row&15)).
// 16B chunks, 16 per 256B row. Kills the 16-way ds_read_b128 bank conflict
// (verified: SQ_LDS_BANK_CONFLICT 7.34M -> 0). Global side is a gather over
// the SAME set of 64B lines, so coalescing is unchanged.
__device__ inline int swz(int chunk) {
  return (chunk & ~15) | ((chunk & 15) ^ ((chunk >> 4) & 15));
}

// ---------------- Kernel 1: L2-normalize rows -> bf16; zero out ----------
__global__ __launch_bounds__(256) void knorm(const float* __restrict__ p0,
                                             const float* __restrict__ p1,
                                             const float* __restrict__ p2,
                                             const float* __restrict__ p3,
                                             short* __restrict__ Bn,
                                             float* __restrict__ out) {
  if (blockIdx.x == 0 && threadIdx.x == 0) out[0] = 0.0f;
  int wave = threadIdx.x >> 6, lane = threadIdx.x & 63;
  int row = blockIdx.x * 4 + wave;                 // 0..8191
  int q = row >> 11, idx = row & (NN - 1);
  const float* src = (q == 0) ? p0 : (q == 1) ? p1 : (q == 2) ? p2 : p3;
  const float2* s2 = (const float2*)(src + (size_t)idx * DD);
  float2 v = s2[lane];
  float ss = v.x * v.x + v.y * v.y;
  #pragma unroll
  for (int sh = 1; sh < 64; sh <<= 1) ss += __shfl_xor(ss, sh, 64);
  float inv = 1.0f / fmaxf(sqrtf(ss), 1e-8f);
  __hip_bfloat162 o;
  o.x = __float2bfloat16(v.x * inv);
  o.y = __float2bfloat16(v.y * inv);
  ((__hip_bfloat162*)(Bn + (size_t)row * DD))[lane] = o;
}

// ---------------- Kernel 2: GEMM + unmasked partial sumexp ----------------
// Grid (32 row tiles, 64 col tiles). 128x128 tile, 4 waves x 64x64 quadrant.
// pS[row][tile] = sum_{cols in tile} exp(2*sim - 2).  No fences, no atomics.
__global__ __launch_bounds__(256) void kgemm(const short* __restrict__ Bn,
                                             float* __restrict__ pS) {
  __shared__ short sA[BM * DD];   // 32 KB (swizzled)
  __shared__ short sB[BN * DD];   // 32 KB (swizzled)
  __shared__ float sS[BM][2];

  int t = threadIdx.x, wave = t >> 6, lane = t & 63;
  int quad = lane >> 4, l16 = lane & 15;

  const short* gA = Bn + (size_t)blockIdx.x * BM * DD;
  const short* gB = Bn + (size_t)blockIdx.y * BN * DD;
  #pragma unroll
  for (int i = 0; i < 8; ++i) {
    int c0 = i * 256 + wave * 64;                  // lane-0 LDS chunk index
    gl_lds16(gA + (size_t)swz(c0 + lane) * 8, sA + (size_t)c0 * 8);
    gl_lds16(gB + (size_t)swz(c0 + lane) * 8, sB + (size_t)c0 * 8);
  }
  __syncthreads();

  int rowHalf = wave >> 1, colHalf = wave & 1;
  f32x4 acc[4][4];
  #pragma unroll
  for (int rf = 0; rf < 4; ++rf)
    #pragma unroll
    for (int cf = 0; cf < 4; ++cf) acc[rf][cf] = (f32x4){0.f, 0.f, 0.f, 0.f};

  #pragma unroll
  for (int k = 0; k < 4; ++k) {
    frag_ab a[4], b[4];
    #pragma unroll
    for (int rf = 0; rf < 4; ++rf) {
      int r_ = rowHalf * 64 + rf * 16 + l16;       // r_ & 15 == l16
      a[rf] = *(const frag_ab*)&sA[(size_t)((r_ << 4) | ((k * 4 + quad) ^ l16)) * 8];
    }
    #pragma unroll
    for (int cf = 0; cf < 4; ++cf) {
      int r_ = colHalf * 64 + cf * 16 + l16;
      b[cf] = *(const frag_ab*)&sB[(size_t)((r_ << 4) | ((k * 4 + quad) ^ l16)) * 8];
    }
    #pragma unroll
    for (int rf = 0; rf < 4; ++rf)
      #pragma unroll
      for (int cf = 0; cf < 4; ++cf)
        acc[rf][cf] = __builtin_amdgcn_mfma_f32_16x16x32_bf16(a[rf], b[cf], acc[rf][cf], 0, 0, 0);
  }

  // Epilogue: partial sum of exp(2*sim-2) over this wave's 64 cols, no mask.
  int grBase = blockIdx.x * BM;
  #pragma unroll
  for (int rf = 0; rf < 4; ++rf) {
    #pragma unroll
    for (int r = 0; r < 4; ++r) {
      int rowLocal = rowHalf * 64 + rf * 16 + quad * 4 + r;
      float s = 0.f;
      #pragma unroll
      for (int cf = 0; cf < 4; ++cf)
        s += __expf(fmaf(acc[rf][cf][r], 2.0f, -2.0f));
      #pragma unroll
      for (int sh = 1; sh < 16; sh <<= 1) s += __shfl_xor(s, sh, 64);
      if (l16 == 0) sS[rowLocal][colHalf] = s;
    }
  }
  __syncthreads();
  if (t < BM)
    pS[(size_t)(grBase + t) * CT + blockIdx.y] = sS[t][0] + sS[t][1];
}

// ---------------- Kernel 3: finisher (32 blocks x 256 thr) ----------------
// Block b handles rows [b*128, b*128+128): merge 64 tile-partials, subtract
// the 3 masked diagonal exps (self, aug3-diag, aug4-diag), add pos term,
// block-reduce, one atomicAdd into out.
__global__ __launch_bounds__(256) void kfin(const short* __restrict__ Bn,
                                            const float* __restrict__ pS,
                                            float* __restrict__ out) {
  int t = threadIdx.x, wave = t >> 6, lane = t & 63;
  int grBase = blockIdx.x * BM;
  __shared__ float sRed[4];

  float wloss = 0.f;                                // valid on lane 0
  for (int rr = wave; rr < BM; rr += 4) {           // 32 rows per wave
    int gr = grBase + rr;
    int idx = gr & (NN - 1), half = gr >> 11;
    float S = pS[(size_t)gr * CT + lane];           // coalesced: 64 tiles
    #pragma unroll
    for (int sh = 1; sh < 64; sh <<= 1) S += __shfl_xor(S, sh, 64);
    // dots vs: self (gr), pos ((1-half)*NN+idx), aug3 (4096+idx), aug4 (6144+idx)
    unsigned int ua = ((const unsigned int*)(Bn + (size_t)gr * DD))[lane];
    unsigned int ub = ((const unsigned int*)(Bn + (size_t)((1 - half) * NN + idx) * DD))[lane];
    unsigned int uc = ((const unsigned int*)(Bn + (size_t)(2 * NN + idx) * DD))[lane];
    unsigned int ud = ((const unsigned int*)(Bn + (size_t)(3 * NN + idx) * DD))[lane];
    float a0 = __uint_as_float((ua & 0xffffu) << 16), a1 = __uint_as_float(ua & 0xffff0000u);
    float b0 = __uint_as_float((ub & 0xffffu) << 16), b1 = __uint_as_float(ub & 0xffff0000u);
    float c0 = __uint_as_float((uc & 0xffffu) << 16), c1 = __uint_as_float(uc & 0xffff0000u);
    float d0 = __uint_as_float((ud & 0xffffu) << 16), d1 = __uint_as_float(ud & 0xffff0000u);
    float daa = a0 * a0 + a1 * a1;
    float dab = a0 * b0 + a1 * b1;
    float dac = a0 * c0 + a1 * c1;
    float dad = a0 * d0 + a1 * d1;
    #pragma unroll
    for (int sh = 1; sh < 64; sh <<= 1) {
      daa += __shfl_xor(daa, sh, 64);
      dab += __shfl_xor(dab, sh, 64);
      dac += __shfl_xor(dac, sh, 64);
      dad += __shfl_xor(dad, sh, 64);
    }
    // subtract masked diagonals: self + aug3 + aug4 (pos block stays)
    float Sc = S - __expf(fmaf(daa, 2.0f, -2.0f))
                 - __expf(fmaf(dac, 2.0f, -2.0f))
                 - __expf(fmaf(dad, 2.0f, -2.0f));
    float loss = (2.0f + __logf(Sc)) - 2.0f * dab;
    if (lane == 0) wloss += loss;
  }
  if (lane == 0) sRed[wave] = wloss;
  __syncthreads();
  if (t == 0)
    atomicAdd(out, (sRed[0] + sRed[1] + sRed[2] + sRed[3]) * (1.0f / (float)TWO_N));
}

extern "C" void kernel_launch(void* const* d_in, const int* in_sizes, int n_in,
                              void* d_out, int out_size, void* d_ws, size_t ws_size,
                              hipStream_t stream) {
  (void)in_sizes; (void)n_in; (void)out_size; (void)ws_size;
  const float* p0 = (const float*)d_in[0];
  const float* p1 = (const float*)d_in[1];
  const float* p2 = (const float*)d_in[2];
  const float* p3 = (const float*)d_in[3];

  // ws layout: Bn bf16 [8192][128] (2 MB) | pS f32 [4096][64] (1 MB)
  short* Bn = (short*)d_ws;
  float* pS = (float*)((char*)d_ws + (size_t)FOUR_N * DD * sizeof(short));
  float* out = (float*)d_out;

  knorm<<<FOUR_N / 4, 256, 0, stream>>>(p0, p1, p2, p3, Bn, out);
  kgemm<<<dim3(TWO_N / BM, FOUR_N / BN), 256, 0, stream>>>(Bn, pS);
  kfin<<<TWO_N / BM, 256, 0, stream>>>(Bn, pS, out);
}